// Round 1
// baseline (4357.997 us; speedup 1.0000x reference)
//
#include <hip/hip_runtime.h>
#include <hip/hip_bf16.h>

// GINBase: N=50000 nodes, E=512000 edges, D=64, L=4 layers. All f32.

#define GIN_N 50000
#define GIN_E 512000

__global__ __launch_bounds__(256) void zero_f32(float* __restrict__ p, int n) {
    int i = blockIdx.x * 256 + threadIdx.x;
    if (i < n) p[i] = 0.f;
}

// node[n][d] = sum_f atom_emb[f][x[n][f]][d]
__global__ __launch_bounds__(256) void atom_encode(const int* __restrict__ x,
        const float* __restrict__ emb, float* __restrict__ node, int N) {
    int idx = blockIdx.x * 256 + threadIdx.x;
    int n = idx >> 6, lane = idx & 63;
    if (n >= N) return;
    float s = 0.f;
#pragma unroll
    for (int f = 0; f < 9; ++f) {
        int v = x[n * 9 + f];
        s += emb[(f * 119 + v) * 64 + lane];
    }
    node[(size_t)n * 64 + lane] = s;
}

// edge[e][d] = sum_f bond_emb[f][ea[e][f]][d]
__global__ __launch_bounds__(256) void bond_encode(const int* __restrict__ ea,
        const float* __restrict__ emb, float* __restrict__ edge, int E) {
    int idx = blockIdx.x * 256 + threadIdx.x;
    int e = idx >> 6, lane = idx & 63;
    if (e >= E) return;
    float s = 0.f;
#pragma unroll
    for (int f = 0; f < 3; ++f) {
        int v = ea[e * 3 + f];
        s += emb[(f * 6 + v) * 64 + lane];
    }
    edge[(size_t)e * 64 + lane] = s;
}

// agg[dst[e]] += relu(node[src[e]] + edge[e])
__global__ __launch_bounds__(256) void msg_scatter(const int* __restrict__ src,
        const int* __restrict__ dst, const float* __restrict__ node,
        const float* __restrict__ edge, float* __restrict__ agg, int E) {
    int idx = blockIdx.x * 256 + threadIdx.x;
    int e = idx >> 6, lane = idx & 63;
    if (e >= E) return;
    int s = src[e], d = dst[e];
    float v = node[(size_t)s * 64 + lane] + edge[(size_t)e * 64 + lane];
    v = fmaxf(v, 0.f);
    unsafeAtomicAdd(&agg[(size_t)d * 64 + lane], v);
}

// Per-node: h=(1+eps)*node+agg; h=relu(h@W1+b1)@W2+b2; LN; node=relu+node
// One wave (64 lanes) per node, 4 nodes per block. N % 4 == 0.
__global__ __launch_bounds__(256) void node_update(float* __restrict__ node,
        const float* __restrict__ agg, const float* __restrict__ epsArr, int l,
        const float* __restrict__ W1, const float* __restrict__ b1,
        const float* __restrict__ W2, const float* __restrict__ b2,
        const float* __restrict__ g, const float* __restrict__ b) {
    __shared__ float xr[4][64];
    __shared__ float hr[4][128];
    const int wave = threadIdx.x >> 6, lane = threadIdx.x & 63;
    const int n = blockIdx.x * 4 + wave;
    const float eps = epsArr[l];

    const float xold = node[(size_t)n * 64 + lane];
    const float xv = (1.f + eps) * xold + agg[(size_t)n * 64 + lane];
    xr[wave][lane] = xv;
    __syncthreads();

    float h0 = b1[lane], h1 = b1[64 + lane];
#pragma unroll 8
    for (int k = 0; k < 64; ++k) {
        float a = xr[wave][k];
        h0 = fmaf(a, W1[k * 128 + lane], h0);
        h1 = fmaf(a, W1[k * 128 + 64 + lane], h1);
    }
    h0 = fmaxf(h0, 0.f);
    h1 = fmaxf(h1, 0.f);
    hr[wave][lane] = h0;
    hr[wave][64 + lane] = h1;
    __syncthreads();

    float o = b2[lane];
#pragma unroll 8
    for (int j = 0; j < 128; ++j)
        o = fmaf(hr[wave][j], W2[j * 64 + lane], o);

    // LayerNorm across the 64 lanes
    float s = o, s2 = o * o;
#pragma unroll
    for (int off = 32; off; off >>= 1) {
        s += __shfl_xor(s, off);
        s2 += __shfl_xor(s2, off);
    }
    float mean = s * (1.f / 64.f);
    float var = s2 * (1.f / 64.f) - mean * mean;
    float y = (o - mean) * rsqrtf(var + 1e-5f) * g[lane] + b[lane];
    node[(size_t)n * 64 + lane] = fmaxf(y, 0.f) + xold;
}

// Edge update: cat=[node[src],node[dst],edge] (192); m=LN(cat@Wu1+bu1);
// edge = relu(m)@Wu2 + bu2 + edge.  One block of 256 threads per 64 edges.
__global__ __launch_bounds__(256) void edge_update(
        const int* __restrict__ src, const int* __restrict__ dst,
        const float* __restrict__ node, float* __restrict__ edge,
        const float* __restrict__ Wu1, const float* __restrict__ bu1,
        const float* __restrict__ ug, const float* __restrict__ ub,
        const float* __restrict__ Wu2, const float* __restrict__ bu2) {
    __shared__ float cat[64][193];   // stride 193 words: bank step 1/row
    __shared__ float eold[64][64];
    const int t = threadIdx.x;
    const int wave = t >> 6, lane = t & 63;
    const long eBase = (long)blockIdx.x * 64;

    // Phase A: stage cat rows (coalesced 256B gathers)
    for (int e = wave; e < 64; e += 4) {
        long ge = eBase + e;
        int s = src[ge], d = dst[ge];
        cat[e][lane]       = node[(size_t)s * 64 + lane];
        cat[e][64 + lane]  = node[(size_t)d * 64 + lane];
        float ev = edge[(size_t)ge * 64 + lane];
        cat[e][128 + lane] = ev;
        eold[e][lane] = ev;
    }
    __syncthreads();

    // Phase B: m = cat @ Wu1 ; 8 edges x 6 cols per thread
    const int te = t & 7;   // rows te*8 .. te*8+7
    const int tj = t >> 3;  // cols tj*6 .. tj*6+5
    float acc[8][6];
#pragma unroll
    for (int i = 0; i < 8; ++i)
#pragma unroll
        for (int c = 0; c < 6; ++c) acc[i][c] = 0.f;

    for (int k = 0; k < 192; ++k) {
        float a[8];
#pragma unroll
        for (int i = 0; i < 8; ++i) a[i] = cat[te * 8 + i][k];
        float w[6];
#pragma unroll
        for (int c = 0; c < 6; ++c) w[c] = Wu1[k * 192 + tj * 6 + c];
#pragma unroll
        for (int i = 0; i < 8; ++i)
#pragma unroll
            for (int c = 0; c < 6; ++c)
                acc[i][c] = fmaf(a[i], w[c], acc[i][c]);
    }
    __syncthreads();   // all reads of cat done before overwrite

#pragma unroll
    for (int i = 0; i < 8; ++i)
#pragma unroll
        for (int c = 0; c < 6; ++c)
            cat[te * 8 + i][tj * 6 + c] = acc[i][c] + bu1[tj * 6 + c];
    __syncthreads();

    // Phase C: LayerNorm(192) + relu, in place. 4 lanes per edge row.
    {
        const int el = t >> 2, q = t & 3;
        float s = 0.f, s2 = 0.f;
#pragma unroll
        for (int jj = 0; jj < 48; ++jj) {
            float v = cat[el][q * 48 + jj];
            s += v;
            s2 += v * v;
        }
        s += __shfl_xor(s, 1);
        s += __shfl_xor(s, 2);
        s2 += __shfl_xor(s2, 1);
        s2 += __shfl_xor(s2, 2);
        float mean = s * (1.f / 192.f);
        float var = s2 * (1.f / 192.f) - mean * mean;
        float rs = rsqrtf(var + 1e-5f);
#pragma unroll
        for (int jj = 0; jj < 48; ++jj) {
            int j = q * 48 + jj;
            float v = (cat[el][j] - mean) * rs * ug[j] + ub[j];
            cat[el][j] = fmaxf(v, 0.f);
        }
    }
    __syncthreads();

    // Phase D: out = relu_m @ Wu2 + bu2 + edge_old ; wave handles 16 edges
    {
        const int d = lane;
        const int eg = wave;
        float acc2[16];
#pragma unroll
        for (int i = 0; i < 16; ++i) acc2[i] = 0.f;
        for (int k = 0; k < 192; ++k) {
            float w = Wu2[k * 64 + d];
#pragma unroll
            for (int i = 0; i < 16; ++i)
                acc2[i] = fmaf(cat[eg * 16 + i][k], w, acc2[i]);
        }
        float bb = bu2[d];
#pragma unroll
        for (int i = 0; i < 16; ++i) {
            int e = eg * 16 + i;
            edge[(size_t)(eBase + e) * 64 + d] = acc2[i] + bb + eold[e][d];
        }
    }
}

extern "C" void kernel_launch(void* const* d_in, const int* in_sizes, int n_in,
                              void* d_out, int out_size, void* d_ws, size_t ws_size,
                              hipStream_t stream) {
    const int*   x         = (const int*)d_in[0];
    const int*   edge_attr = (const int*)d_in[1];
    const int*   edge_index= (const int*)d_in[2];
    const float* atom_emb  = (const float*)d_in[3];
    const float* bond_emb  = (const float*)d_in[4];
    const float* eps       = (const float*)d_in[5];
    const float* W1        = (const float*)d_in[6];
    const float* b1        = (const float*)d_in[7];
    const float* W2        = (const float*)d_in[8];
    const float* b2        = (const float*)d_in[9];
    const float* ln_g      = (const float*)d_in[10];
    const float* ln_b      = (const float*)d_in[11];
    const float* Wu1       = (const float*)d_in[12];
    const float* bu1       = (const float*)d_in[13];
    const float* ug        = (const float*)d_in[14];
    const float* ub        = (const float*)d_in[15];
    const float* Wu2       = (const float*)d_in[16];
    const float* bu2       = (const float*)d_in[17];

    const int N = GIN_N, E = GIN_E;
    const int* src = edge_index;
    const int* dst = edge_index + E;

    float* node = (float*)d_out;                    // [N,64]
    float* edge = (float*)d_out + (size_t)N * 64;   // [E,64]
    float* agg  = (float*)d_ws;                     // [N,64] scratch

    atom_encode<<<(N * 64) / 256, 256, 0, stream>>>(x, atom_emb, node, N);
    bond_encode<<<(E * 64) / 256, 256, 0, stream>>>(edge_attr, bond_emb, edge, E);

    for (int l = 0; l < 4; ++l) {
        zero_f32<<<(N * 64) / 256, 256, 0, stream>>>(agg, N * 64);
        msg_scatter<<<(E * 64) / 256, 256, 0, stream>>>(src, dst, node, edge, agg, E);
        node_update<<<N / 4, 256, 0, stream>>>(node, agg, eps, l,
            W1 + (size_t)l * 64 * 128, b1 + (size_t)l * 128,
            W2 + (size_t)l * 128 * 64, b2 + (size_t)l * 64,
            ln_g + (size_t)l * 64, ln_b + (size_t)l * 64);
        edge_update<<<E / 64, 256, 0, stream>>>(src, dst, node, edge,
            Wu1 + (size_t)l * 192 * 192, bu1 + (size_t)l * 192,
            ug + (size_t)l * 192, ub + (size_t)l * 192,
            Wu2 + (size_t)l * 192 * 64, bu2 + (size_t)l * 64);
    }
}

// Round 2
// 1777.504 us; speedup vs baseline: 2.4518x; 2.4518x over previous
//
#include <hip/hip_runtime.h>
#include <hip/hip_bf16.h>

// GINBase: N=50000 nodes, E=512000 edges, D=64, L=4 layers.
// Edge-update GEMMs via bf16 MFMA with hi/lo split (f32-level accuracy).

#define GIN_N 50000
#define GIN_E 512000

typedef __attribute__((ext_vector_type(8))) short short8;
typedef __attribute__((ext_vector_type(4))) float f32x4;

__device__ __forceinline__ unsigned short bf16r(float x) {
    unsigned int u = __builtin_bit_cast(unsigned int, x);
    u += 0x7fffu + ((u >> 16) & 1u);
    return (unsigned short)(u >> 16);
}
__device__ __forceinline__ float bf16f(unsigned short h) {
    unsigned int u = ((unsigned int)h) << 16;
    return __builtin_bit_cast(float, u);
}

__global__ __launch_bounds__(256) void zero_f32(float* __restrict__ p, int n) {
    int i = blockIdx.x * 256 + threadIdx.x;
    if (i < n) p[i] = 0.f;
}

__global__ __launch_bounds__(256) void atom_encode(const int* __restrict__ x,
        const float* __restrict__ emb, float* __restrict__ node, int N) {
    int idx = blockIdx.x * 256 + threadIdx.x;
    int n = idx >> 6, lane = idx & 63;
    if (n >= N) return;
    float s = 0.f;
#pragma unroll
    for (int f = 0; f < 9; ++f) {
        int v = x[n * 9 + f];
        s += emb[(f * 119 + v) * 64 + lane];
    }
    node[(size_t)n * 64 + lane] = s;
}

__global__ __launch_bounds__(256) void bond_encode(const int* __restrict__ ea,
        const float* __restrict__ emb, float* __restrict__ edge, int E) {
    int idx = blockIdx.x * 256 + threadIdx.x;
    int e = idx >> 6, lane = idx & 63;
    if (e >= E) return;
    float s = 0.f;
#pragma unroll
    for (int f = 0; f < 3; ++f) {
        int v = ea[e * 3 + f];
        s += emb[(f * 6 + v) * 64 + lane];
    }
    edge[(size_t)e * 64 + lane] = s;
}

__global__ __launch_bounds__(256) void msg_scatter(const int* __restrict__ src,
        const int* __restrict__ dst, const float* __restrict__ node,
        const float* __restrict__ edge, float* __restrict__ agg, int E) {
    int idx = blockIdx.x * 256 + threadIdx.x;
    int e = idx >> 6, lane = idx & 63;
    if (e >= E) return;
    int s = src[e], d = dst[e];
    float v = node[(size_t)s * 64 + lane] + edge[(size_t)e * 64 + lane];
    v = fmaxf(v, 0.f);
    unsafeAtomicAdd(&agg[(size_t)d * 64 + lane], v);
}

__global__ __launch_bounds__(256) void node_update(float* __restrict__ node,
        const float* __restrict__ agg, const float* __restrict__ epsArr, int l,
        const float* __restrict__ W1, const float* __restrict__ b1,
        const float* __restrict__ W2, const float* __restrict__ b2,
        const float* __restrict__ g, const float* __restrict__ b) {
    __shared__ float xr[4][64];
    __shared__ float hr[4][128];
    const int wave = threadIdx.x >> 6, lane = threadIdx.x & 63;
    const int n = blockIdx.x * 4 + wave;
    const float eps = epsArr[l];

    const float xold = node[(size_t)n * 64 + lane];
    const float xv = (1.f + eps) * xold + agg[(size_t)n * 64 + lane];
    xr[wave][lane] = xv;
    __syncthreads();

    float h0 = b1[lane], h1 = b1[64 + lane];
#pragma unroll 8
    for (int k = 0; k < 64; ++k) {
        float a = xr[wave][k];
        h0 = fmaf(a, W1[k * 128 + lane], h0);
        h1 = fmaf(a, W1[k * 128 + 64 + lane], h1);
    }
    h0 = fmaxf(h0, 0.f);
    h1 = fmaxf(h1, 0.f);
    hr[wave][lane] = h0;
    hr[wave][64 + lane] = h1;
    __syncthreads();

    float o = b2[lane];
#pragma unroll 8
    for (int j = 0; j < 128; ++j)
        o = fmaf(hr[wave][j], W2[j * 64 + lane], o);

    float s = o, s2 = o * o;
#pragma unroll
    for (int off = 32; off; off >>= 1) {
        s += __shfl_xor(s, off);
        s2 += __shfl_xor(s2, off);
    }
    float mean = s * (1.f / 64.f);
    float var = s2 * (1.f / 64.f) - mean * mean;
    float y = (o - mean) * rsqrtf(var + 1e-5f) * g[lane] + b[lane];
    node[(size_t)n * 64 + lane] = fmaxf(y, 0.f) + xold;
}

// ---- weight pre-pack into MFMA B-fragment order (hi/lo bf16) ----
// pb1: [layer(4)][frag(72 = ks*12+t)][hi 64*8 | lo 64*8] bf16
__global__ __launch_bounds__(256) void pack_w1(const float* __restrict__ W,
                                               unsigned short* __restrict__ out) {
    int tid = blockIdx.x * 256 + threadIdx.x;   // 4*72*64 = 18432 threads
    int lane = tid & 63;
    int frag = (tid >> 6) % 72;
    int layer = tid / (72 * 64);
    int ks = frag / 12, t = frag % 12;
    int k0 = ks * 32 + (lane >> 4) * 8;
    int col = t * 16 + (lane & 15);
    const float* w = W + (size_t)layer * 192 * 192;
    unsigned short* o = out + ((size_t)(layer * 72 + frag)) * 1024 + lane * 8;
#pragma unroll
    for (int j = 0; j < 8; ++j) {
        float x = w[(k0 + j) * 192 + col];
        unsigned short hi = bf16r(x);
        o[j] = hi;
        o[512 + j] = bf16r(x - bf16f(hi));
    }
}

// pb2: [layer(4)][frag(24 = ks*4+t)][hi 64*8 | lo 64*8]
__global__ __launch_bounds__(256) void pack_w2(const float* __restrict__ W,
                                               unsigned short* __restrict__ out) {
    int tid = blockIdx.x * 256 + threadIdx.x;   // 4*24*64 = 6144 threads
    int lane = tid & 63;
    int frag = (tid >> 6) % 24;
    int layer = tid / (24 * 64);
    int ks = frag / 4, t = frag % 4;
    int k0 = ks * 32 + (lane >> 4) * 8;
    int col = t * 16 + (lane & 15);
    const float* w = W + (size_t)layer * 192 * 64;
    unsigned short* o = out + ((size_t)(layer * 24 + frag)) * 1024 + lane * 8;
#pragma unroll
    for (int j = 0; j < 8; ++j) {
        float x = w[(k0 + j) * 64 + col];
        unsigned short hi = bf16r(x);
        o[j] = hi;
        o[512 + j] = bf16r(x - bf16f(hi));
    }
}

// ---- MFMA edge update: 64 edges / block, 4 waves, N-split over cols ----
__global__ __launch_bounds__(256, 3) void edge_update_mfma(
        const int* __restrict__ src, const int* __restrict__ dst,
        const float* __restrict__ node, float* __restrict__ edge,
        const unsigned short* __restrict__ pb1, const unsigned short* __restrict__ pb2,
        const float* __restrict__ bu1, const float* __restrict__ ug,
        const float* __restrict__ ub, const float* __restrict__ bu2) {
    __shared__ unsigned short catHi[64][200];   // stride 200 -> 2-way max conflicts
    __shared__ unsigned short catLo[64][200];
    __shared__ float pS[4][64], pS2[4][64];
    __shared__ float lnM[64], lnR[64];

    const int t256 = threadIdx.x;
    const int w = t256 >> 6, lane = t256 & 63;
    const int g = lane >> 4, c0 = lane & 15;
    const long eB = (long)blockIdx.x * 64;

    // stage: wave w stages rows [w*16, w*16+16) as hi/lo bf16
#pragma unroll
    for (int i = 0; i < 16; ++i) {
        int r = w * 16 + i;
        long ge = eB + r;
        int s = src[ge], d = dst[ge];
        float xs = node[(size_t)s * 64 + lane];
        float xd = node[(size_t)d * 64 + lane];
        float xe = edge[(size_t)ge * 64 + lane];
        unsigned short h;
        h = bf16r(xs); catHi[r][lane] = h;       catLo[r][lane]       = bf16r(xs - bf16f(h));
        h = bf16r(xd); catHi[r][64 + lane] = h;  catLo[r][64 + lane]  = bf16r(xd - bf16f(h));
        h = bf16r(xe); catHi[r][128 + lane] = h; catLo[r][128 + lane] = bf16r(xe - bf16f(h));
    }
    __syncthreads();

    // GEMM1: wave w computes cols [w*48, w*48+48), all 64 rows.
    f32x4 acc[4][3];
#pragma unroll
    for (int sp = 0; sp < 4; ++sp)
#pragma unroll
        for (int lt = 0; lt < 3; ++lt) acc[sp][lt] = (f32x4)0.f;

#pragma unroll
    for (int ks = 0; ks < 6; ++ks) {
        short8 aH[4], aL[4];
#pragma unroll
        for (int sp = 0; sp < 4; ++sp) {
            aH[sp] = *(const short8*)&catHi[sp * 16 + c0][ks * 32 + g * 8];
            aL[sp] = *(const short8*)&catLo[sp * 16 + c0][ks * 32 + g * 8];
        }
#pragma unroll
        for (int lt = 0; lt < 3; ++lt) {
            int frag = ks * 12 + (w * 3 + lt);
            const unsigned short* pb = pb1 + (size_t)frag * 1024 + lane * 8;
            short8 bH = *(const short8*)pb;
            short8 bL = *(const short8*)(pb + 512);
#pragma unroll
            for (int sp = 0; sp < 4; ++sp) {
                acc[sp][lt] = __builtin_amdgcn_mfma_f32_16x16x32_bf16(aH[sp], bH, acc[sp][lt], 0, 0, 0);
                acc[sp][lt] = __builtin_amdgcn_mfma_f32_16x16x32_bf16(aH[sp], bL, acc[sp][lt], 0, 0, 0);
                acc[sp][lt] = __builtin_amdgcn_mfma_f32_16x16x32_bf16(aL[sp], bH, acc[sp][lt], 0, 0, 0);
            }
        }
    }

    // + bias, row partial sums (this wave's 48 cols)
    float bs[3];
#pragma unroll
    for (int lt = 0; lt < 3; ++lt) bs[lt] = bu1[w * 48 + lt * 16 + c0];

    float s1[4][4], s2v[4][4];   // [strip][reg]
#pragma unroll
    for (int sp = 0; sp < 4; ++sp)
#pragma unroll
        for (int rg = 0; rg < 4; ++rg) { s1[sp][rg] = 0.f; s2v[sp][rg] = 0.f; }
#pragma unroll
    for (int sp = 0; sp < 4; ++sp)
#pragma unroll
        for (int lt = 0; lt < 3; ++lt)
#pragma unroll
            for (int rg = 0; rg < 4; ++rg) {
                float v = acc[sp][lt][rg] + bs[lt];
                acc[sp][lt][rg] = v;
                s1[sp][rg] += v;
                s2v[sp][rg] += v * v;
            }
#pragma unroll
    for (int off = 1; off < 16; off <<= 1)
#pragma unroll
        for (int sp = 0; sp < 4; ++sp)
#pragma unroll
            for (int rg = 0; rg < 4; ++rg) {
                s1[sp][rg] += __shfl_xor(s1[sp][rg], off);
                s2v[sp][rg] += __shfl_xor(s2v[sp][rg], off);
            }
    if (c0 == 0) {
#pragma unroll
        for (int sp = 0; sp < 4; ++sp)
#pragma unroll
            for (int rg = 0; rg < 4; ++rg) {
                int r = sp * 16 + g * 4 + rg;
                pS[w][r] = s1[sp][rg];
                pS2[w][r] = s2v[sp][rg];
            }
    }
    __syncthreads();
    if (t256 < 64) {
        float a = pS[0][t256] + pS[1][t256] + pS[2][t256] + pS[3][t256];
        float b = pS2[0][t256] + pS2[1][t256] + pS2[2][t256] + pS2[3][t256];
        float mean = a * (1.f / 192.f);
        float var = b * (1.f / 192.f) - mean * mean;
        lnM[t256] = mean;
        lnR[t256] = rsqrtf(var + 1e-5f);
    }
    __syncthreads();

    // normalize + relu, write m (hi/lo) back into cat buffers
#pragma unroll
    for (int sp = 0; sp < 4; ++sp)
#pragma unroll
        for (int lt = 0; lt < 3; ++lt) {
            int col = w * 48 + lt * 16 + c0;
            float gg = ug[col], bb = ub[col];
#pragma unroll
            for (int rg = 0; rg < 4; ++rg) {
                int r = sp * 16 + g * 4 + rg;
                float v = (acc[sp][lt][rg] - lnM[r]) * lnR[r] * gg + bb;
                v = fmaxf(v, 0.f);
                unsigned short h = bf16r(v);
                catHi[r][col] = h;
                catLo[r][col] = bf16r(v - bf16f(h));
            }
        }
    __syncthreads();

    // GEMM2: wave w computes col tile t=w (cols w*16..w*16+15), all rows
    f32x4 ac2[4];
#pragma unroll
    for (int sp = 0; sp < 4; ++sp) ac2[sp] = (f32x4)0.f;
#pragma unroll
    for (int ks = 0; ks < 6; ++ks) {
        int frag = ks * 4 + w;
        const unsigned short* pb = pb2 + (size_t)frag * 1024 + lane * 8;
        short8 bH = *(const short8*)pb;
        short8 bL = *(const short8*)(pb + 512);
#pragma unroll
        for (int sp = 0; sp < 4; ++sp) {
            short8 aH = *(const short8*)&catHi[sp * 16 + c0][ks * 32 + g * 8];
            short8 aL = *(const short8*)&catLo[sp * 16 + c0][ks * 32 + g * 8];
            ac2[sp] = __builtin_amdgcn_mfma_f32_16x16x32_bf16(aH, bH, ac2[sp], 0, 0, 0);
            ac2[sp] = __builtin_amdgcn_mfma_f32_16x16x32_bf16(aH, bL, ac2[sp], 0, 0, 0);
            ac2[sp] = __builtin_amdgcn_mfma_f32_16x16x32_bf16(aL, bH, ac2[sp], 0, 0, 0);
        }
    }

    // epilogue: out = acc + bu2 + edge_old
    float bb2 = bu2[w * 16 + c0];
#pragma unroll
    for (int sp = 0; sp < 4; ++sp)
#pragma unroll
        for (int rg = 0; rg < 4; ++rg) {
            size_t off = (size_t)(eB + sp * 16 + g * 4 + rg) * 64 + w * 16 + c0;
            edge[off] = ac2[sp][rg] + bb2 + edge[off];
        }
}

extern "C" void kernel_launch(void* const* d_in, const int* in_sizes, int n_in,
                              void* d_out, int out_size, void* d_ws, size_t ws_size,
                              hipStream_t stream) {
    const int*   x         = (const int*)d_in[0];
    const int*   edge_attr = (const int*)d_in[1];
    const int*   edge_index= (const int*)d_in[2];
    const float* atom_emb  = (const float*)d_in[3];
    const float* bond_emb  = (const float*)d_in[4];
    const float* eps       = (const float*)d_in[5];
    const float* W1        = (const float*)d_in[6];
    const float* b1        = (const float*)d_in[7];
    const float* W2        = (const float*)d_in[8];
    const float* b2        = (const float*)d_in[9];
    const float* ln_g      = (const float*)d_in[10];
    const float* ln_b      = (const float*)d_in[11];
    const float* Wu1       = (const float*)d_in[12];
    const float* bu1       = (const float*)d_in[13];
    const float* ug        = (const float*)d_in[14];
    const float* ub        = (const float*)d_in[15];
    const float* Wu2       = (const float*)d_in[16];
    const float* bu2       = (const float*)d_in[17];

    const int N = GIN_N, E = GIN_E;
    const int* src = edge_index;
    const int* dst = edge_index + E;

    float* node = (float*)d_out;                    // [N,64]
    float* edge = (float*)d_out + (size_t)N * 64;   // [E,64]

    float* agg = (float*)d_ws;                      // [N,64] scratch (12.8 MB)
    unsigned short* pb1 = (unsigned short*)((char*)d_ws + (size_t)N * 64 * 4);
    unsigned short* pb2 = pb1 + (size_t)4 * 72 * 1024;

    pack_w1<<<(4 * 72 * 64) / 256, 256, 0, stream>>>(Wu1, pb1);
    pack_w2<<<(4 * 24 * 64) / 256, 256, 0, stream>>>(Wu2, pb2);

    atom_encode<<<(N * 64) / 256, 256, 0, stream>>>(x, atom_emb, node, N);
    bond_encode<<<(E * 64) / 256, 256, 0, stream>>>(edge_attr, bond_emb, edge, E);

    for (int l = 0; l < 4; ++l) {
        zero_f32<<<(N * 64) / 256, 256, 0, stream>>>(agg, N * 64);
        msg_scatter<<<(E * 64) / 256, 256, 0, stream>>>(src, dst, node, edge, agg, E);
        node_update<<<N / 4, 256, 0, stream>>>(node, agg, eps, l,
            W1 + (size_t)l * 64 * 128, b1 + (size_t)l * 128,
            W2 + (size_t)l * 128 * 64, b2 + (size_t)l * 64,
            ln_g + (size_t)l * 64, ln_b + (size_t)l * 64);
        edge_update_mfma<<<E / 64, 256, 0, stream>>>(src, dst, node, edge,
            pb1 + (size_t)l * 72 * 1024, pb2 + (size_t)l * 24 * 1024,
            bu1 + (size_t)l * 192,
            ug + (size_t)l * 192, ub + (size_t)l * 192,
            bu2 + (size_t)l * 64);
    }
}